// Round 6
// baseline (294.937 us; speedup 1.0000x reference)
//
#include <hip/hip_runtime.h>

#define SEQ    512
#define NH     16
#define DH     64
#define DMODEL 1024
#define NB     16
#define MROWS  (NB*SEQ)      // 8192
#define MAXL   512

typedef _Float16 f16;
typedef f16  f16x8 __attribute__((ext_vector_type(8)));
typedef f16  f16x4 __attribute__((ext_vector_type(4)));
typedef float f32x4  __attribute__((ext_vector_type(4)));
typedef float f32x16 __attribute__((ext_vector_type(16)));

// async global->LDS, 16B/lane; global addr per-lane, LDS dest = wave-uniform base + lane*16
__device__ static inline void gll16(const f16* g, f16* l) {
    __builtin_amdgcn_global_load_lds(
        (const __attribute__((address_space(1))) void*)(g),
        (__attribute__((address_space(3))) void*)(l), 16, 0, 0);
}

// ---------------------------------------------------------------------------
// prep: W transposes only (x-convert folded into gemm1).
// blocks 0..3071 -> wqkv (1024x3072) -> wqkvT (3072x1024)
// blocks 3072..4095 -> wout (1024x1024) -> woutT
// ---------------------------------------------------------------------------
__global__ __launch_bounds__(256)
void prep(const float* __restrict__ wqkv, f16* __restrict__ wqkvT,
          const float* __restrict__ wout, f16* __restrict__ woutT)
{
    const int bid = blockIdx.x, t = threadIdx.x;
    __shared__ float tile[32][33];
    const float* in; f16* out; int C, gx, gy;
    if (bid < 3072) {
        in = wqkv; out = wqkvT; C = 3072;
        gx = bid % 96; gy = bid / 96;
    } else {
        int b2 = bid - 3072; in = wout; out = woutT; C = 1024;
        gx = b2 & 31; gy = b2 >> 5;
    }
    const int R = 1024;
    int tx = t & 31, ty = t >> 5;
    int c0 = gx * 32, r0 = gy * 32;
    #pragma unroll
    for (int i = 0; i < 4; ++i)
        tile[ty + i * 8][tx] = in[(size_t)(r0 + ty + i * 8) * C + c0 + tx];
    __syncthreads();
    #pragma unroll
    for (int i = 0; i < 4; ++i)
        out[(size_t)(c0 + ty + i * 8) * R + r0 + tx] = (f16)tile[tx][ty + i * 8];
}

// ---------------------------------------------------------------------------
// MFMA GEMM, 32x32x16 f16: C(M x N) = A @ Bt^T + bias
// 128x128 tile, BK=64, 256 threads (2x2 waves, wave tile 64x64 = 2x2 of 32x32).
// LDS layout [row][chunk8 ^ (row&7)] -> all b128 reads/writes conflict-free.
// CVTA=1: A is fp32 (x), staged via load+cvt+ds_write; else f16 via global_load_lds.
// MODE 0 epilogue (QKV): Q -> [b][h][n][d] plain
//                        K -> [b][h][n][d], d-chunk8 XOR (n&7)
//                        V -> [b][h][d][n] transposed, n-chunk8 XOR (d&7)
// MODE 1 epilogue: fp32 row-major C + bias
// ---------------------------------------------------------------------------
template<int MODE, int CVTA>
__global__ __launch_bounds__(256)
void gemm_mfma(const float* __restrict__ A32, const f16* __restrict__ A16,
               const f16* __restrict__ Bt,
               const float* __restrict__ bias, int N, int K,
               float* __restrict__ Cout,
               f16* __restrict__ qb, f16* __restrict__ kb, f16* __restrict__ vb)
{
    __shared__ f16 As[128 * 64];
    __shared__ f16 Bs[128 * 64];
    const int t = threadIdx.x;
    const int lane = t & 63, w = t >> 6;
    const int l32 = lane & 31, half = lane >> 5;
    const int m0 = blockIdx.y * 128, n0 = blockIdx.x * 128;
    const int wm = (w & 1) * 64, wn = (w >> 1) * 64;

    f32x16 acc[2][2];
    #pragma unroll
    for (int i = 0; i < 2; ++i)
        #pragma unroll
        for (int j = 0; j < 2; ++j)
            acc[i][j] = (f32x16)(0.f);

    // f16 async staging mapping (B always; A when CVTA==0)
    const int sr8 = lane >> 3;
    const int sc8 = (lane & 7) ^ sr8;
    const f16* bgp = Bt + (size_t)(n0 + w * 32 + sr8) * K + sc8 * 8;
    f16* bsl = Bs + w * 2048;
    const f16* agp = CVTA ? nullptr
                          : A16 + (size_t)(m0 + w * 32 + sr8) * K + sc8 * 8;
    f16* asl = As + w * 2048;

    // CVTA staging mapping: thread t covers row t/2, 32 k-cols at (t&1)*32
    const int crow = t >> 1, chalf = t & 1;
    const float* agp32 = CVTA ? A32 + (size_t)(m0 + crow) * K + chalf * 32 : nullptr;
    const int cr8 = crow & 7;

    for (int k0 = 0; k0 < K; k0 += 64) {
        __syncthreads();
        #pragma unroll
        for (int c = 0; c < 4; ++c)
            gll16(bgp + k0 + c * 8 * K, bsl + c * 512);
        if (CVTA) {
            float4 v[8];
            #pragma unroll
            for (int i = 0; i < 8; ++i)
                v[i] = *(const float4*)(agp32 + k0 + i * 4);
            #pragma unroll
            for (int c = 0; c < 4; ++c) {
                f16x8 hh = { (f16)v[2*c].x, (f16)v[2*c].y, (f16)v[2*c].z, (f16)v[2*c].w,
                             (f16)v[2*c+1].x, (f16)v[2*c+1].y, (f16)v[2*c+1].z, (f16)v[2*c+1].w };
                int c8 = (chalf * 4 + c) ^ cr8;
                *(f16x8*)&As[crow * 64 + c8 * 8] = hh;
            }
        } else {
            #pragma unroll
            for (int c = 0; c < 4; ++c)
                gll16(agp + k0 + c * 8 * K, asl + c * 512);
        }
        __syncthreads();

        #pragma unroll
        for (int ks = 0; ks < 4; ++ks) {
            f16x8 af[2], bf[2];
            #pragma unroll
            for (int ms = 0; ms < 2; ++ms) {
                int row = wm + ms * 32 + l32;
                int c8 = (ks * 2 + half) ^ (row & 7);
                af[ms] = *(const f16x8*)&As[row * 64 + c8 * 8];
            }
            #pragma unroll
            for (int ns = 0; ns < 2; ++ns) {
                int row = wn + ns * 32 + l32;
                int c8 = (ks * 2 + half) ^ (row & 7);
                bf[ns] = *(const f16x8*)&Bs[row * 64 + c8 * 8];
            }
            #pragma unroll
            for (int ms = 0; ms < 2; ++ms)
                #pragma unroll
                for (int ns = 0; ns < 2; ++ns)
                    acc[ms][ns] = __builtin_amdgcn_mfma_f32_32x32x16_f16(
                        af[ms], bf[ns], acc[ms][ns], 0, 0, 0);
        }
    }

    // C/D layout: col = l32 (n), row = (reg&3) + 8*(reg>>2) + 4*half (m)
    const int bb_ = m0 >> 9;   // batch fixed per block (128-row span within one b)
    #pragma unroll
    for (int ns = 0; ns < 2; ++ns) {
        int col = n0 + wn + ns * 32 + l32;
        float bv = bias[col];
        if (MODE == 0) {
            int which = col >> 10;
            int hh = (col & 1023) >> 6, d = col & 63;
            #pragma unroll
            for (int ms = 0; ms < 2; ++ms) {
                int rowbase = wm + ms * 32 + 4 * half + (m0 & 511);
                #pragma unroll
                for (int g = 0; g < 4; ++g) {
                    int n_ = rowbase + 8 * g;     // multiple of 4
                    if (which == 0) {
                        #pragma unroll
                        for (int j = 0; j < 4; ++j)
                            qb[((size_t)(bb_ * NH + hh) * SEQ + n_ + j) * DH + d] =
                                (f16)(acc[ms][ns][g * 4 + j] + bv);
                    } else if (which == 2) {
                        f16x4 pk;
                        #pragma unroll
                        for (int j = 0; j < 4; ++j)
                            pk[j] = (f16)(acc[ms][ns][g * 4 + j] + bv);
                        int c8s = ((n_ >> 3) & 7) ^ (d & 7);
                        *(f16x4*)(vb + ((size_t)(bb_ * NH + hh) * DH + d) * SEQ
                                     + (n_ & ~63) + c8s * 8 + (n_ & 7)) = pk;
                    } else {
                        #pragma unroll
                        for (int j = 0; j < 4; ++j) {
                            int n = n_ + j;
                            int dd = (((d >> 3) ^ (n & 7)) * 8) + (d & 7);
                            kb[((size_t)(bb_ * NH + hh) * SEQ + n) * DH + dd] =
                                (f16)(acc[ms][ns][g * 4 + j] + bv);
                        }
                    }
                }
            }
        } else {
            #pragma unroll
            for (int ms = 0; ms < 2; ++ms) {
                int rowbase = m0 + wm + ms * 32 + 4 * half;
                #pragma unroll
                for (int g = 0; g < 4; ++g)
                    #pragma unroll
                    for (int j = 0; j < 4; ++j)
                        Cout[(size_t)(rowbase + 8 * g + j) * N + col] =
                            acc[ms][ns][g * 4 + j] + bv;
            }
        }
    }
}

// ---------------------------------------------------------------------------
// MFMA attention, one block per (b,h), 512 threads = 8 waves, wave owns 64
// q-rows. 4 key-tiles of 128, K/V double-buffered in LDS (prefetch kt+1
// before computing kt -> staging latency hidden; 5 barriers/block).
// Transposed-S (no online rescale), per-lane scalar row-sum.
// ---------------------------------------------------------------------------
__global__ __launch_bounds__(512)
void attn_mfma(const f16* __restrict__ qb, const f16* __restrict__ kb,
               const f16* __restrict__ vb, const float* __restrict__ rel,
               f16* __restrict__ ob)
{
    __shared__ f16 Ks[2][128 * 64];   // [key][d-chunk8 ^ (key&7)]  2x16 KB
    __shared__ f16 Vt[2][64 * 128];   // [d][key-chunk8 ^ (d&7) per 64]  2x16 KB
    __shared__ f16 Pw[8][16 * 64];    // wave-private P  16 KB
    __shared__ float relh[1024];      // rel[:,h] * log2(e)  4 KB

    const int t = threadIdx.x;
    const int lane = t & 63, w = t >> 6;
    const int quad = lane >> 4, l16 = lane & 15;
    const int xr = l16 & 7;
    const int bh = blockIdx.x;
    const int h = bh & 15, b = bh >> 4;

    for (int i = t; i < 2 * MAXL - 1; i += 512)
        relh[i] = rel[i * NH + h] * 1.44269504f;

    f16x8 qf[4][2];
    #pragma unroll
    for (int c = 0; c < 4; ++c) {
        const f16* qrow = qb + ((size_t)bh * SEQ + w * 64 + c * 16 + l16) * DH + quad * 8;
        qf[c][0] = *(const f16x8*)(qrow);
        qf[c][1] = *(const f16x8*)(qrow + 32);
    }

    f32x4 o[4][4];
    float lsum[4];
    #pragma unroll
    for (int c = 0; c < 4; ++c) {
        lsum[c] = 0.f;
        #pragma unroll
        for (int dt = 0; dt < 4; ++dt) o[c][dt] = f32x4{0.f, 0.f, 0.f, 0.f};
    }

    const f16* kbase = kb + (size_t)bh * SEQ * DH;
    const f16* vbase = vb + (size_t)bh * DH * SEQ;
    f16* pw = &Pw[w][0];

    // stage tile kt into buffer buf
    auto stage = [&](int kt, int buf) {
        #pragma unroll
        for (int r = 0; r < 2; ++r) {
            const f16* src = kbase + (size_t)(kt * 128 + r * 64 + w * 8 + (lane >> 3)) * DH
                           + (lane & 7) * 8;
            gll16(src, Ks[buf] + r * 4096 + w * 512);
        }
        #pragma unroll
        for (int r = 0; r < 2; ++r) {
            const f16* src = vbase + (size_t)(r * 32 + w * 4 + (lane >> 4)) * SEQ
                           + kt * 128 + ((lane & 15) >> 3) * 64 + (lane & 7) * 8;
            gll16(src, Vt[buf] + r * 4096 + w * 512);
        }
    };

    stage(0, 0);
    __syncthreads();

    for (int kt = 0; kt < 4; ++kt) {
        if (kt < 3) stage(kt + 1, (kt + 1) & 1);
        const f16* ks = Ks[kt & 1];
        const f16* vt = Vt[kt & 1];

        #pragma unroll
        for (int c = 0; c < 4; ++c) {
            f32x4 sT[8];
            #pragma unroll
            for (int mt = 0; mt < 8; ++mt) {
                const f16* kr = &ks[(mt * 16 + l16) * 64];
                f16x8 a0 = *(const f16x8*)(kr + ((quad ^ xr) * 8));
                f16x8 a1 = *(const f16x8*)(kr + (((4 + quad) ^ xr) * 8));
                f32x4 s = f32x4{0.f, 0.f, 0.f, 0.f};
                s = __builtin_amdgcn_mfma_f32_16x16x32_f16(a0, qf[c][0], s, 0, 0, 0);
                s = __builtin_amdgcn_mfma_f32_16x16x32_f16(a1, qf[c][1], s, 0, 0, 0);
                sT[mt] = s;
            }

            const int cb0 = w * 64 + c * 16 + l16 + (MAXL - 1) - kt * 128 - quad * 4;
            #pragma unroll
            for (int g = 0; g < 2; ++g) {
                #pragma unroll
                for (int m4 = 0; m4 < 4; ++m4) {
                    int mt = g * 4 + m4;
                    f16x4 pk;
                    #pragma unroll
                    for (int reg = 0; reg < 4; ++reg) {
                        float e = exp2f(fmaf(sT[mt][reg], 0.180336878f,
                                             relh[cb0 - mt * 16 - reg]));
                        lsum[c] += e;
                        pk[reg] = (f16)e;
                    }
                    int c8 = (m4 * 2 + (quad >> 1)) ^ xr;
                    *(f16x4*)&pw[l16 * 64 + c8 * 8 + (quad & 1) * 4] = pk;
                }
                __builtin_amdgcn_s_waitcnt(0xC07F);   // lgkmcnt(0), wave-private P

                #pragma unroll
                for (int s2 = 0; s2 < 2; ++s2) {
                    f16x8 pa = *(const f16x8*)&pw[l16 * 64 + (((s2 * 4 + quad) ^ xr) * 8)];
                    #pragma unroll
                    for (int dt = 0; dt < 4; ++dt) {
                        const f16* vr = &vt[(dt * 16 + l16) * 128 + g * 64];
                        f16x8 vb8 = *(const f16x8*)(vr + (((s2 * 4 + quad) ^ xr) * 8));
                        o[c][dt] = __builtin_amdgcn_mfma_f32_16x16x32_f16(
                            pa, vb8, o[c][dt], 0, 0, 0);
                    }
                }
            }
        }
        __syncthreads();   // drains prefetch vmcnt + joins waves
    }

    #pragma unroll
    for (int c = 0; c < 4; ++c) {
        float ls = lsum[c];
        ls += __shfl_xor(ls, 16, 64);
        ls += __shfl_xor(ls, 32, 64);
        #pragma unroll
        for (int reg = 0; reg < 4; ++reg) {
            float inv = 1.0f / __shfl(ls, quad * 4 + reg, 64);
            size_t rbase = ((size_t)b * SEQ + w * 64 + c * 16 + quad * 4 + reg) * DMODEL
                         + h * DH;
            #pragma unroll
            for (int dt = 0; dt < 4; ++dt)
                ob[rbase + dt * 16 + l16] = (f16)(o[c][dt][reg] * inv);
        }
    }
}

// ---------------------------------------------------------------------------
extern "C" void kernel_launch(void* const* d_in, const int* in_sizes, int n_in,
                              void* d_out, int out_size, void* d_ws, size_t ws_size,
                              hipStream_t stream)
{
    const float* x    = (const float*)d_in[0];
    const float* wqkv = (const float*)d_in[1];
    const float* bqkv = (const float*)d_in[2];
    const float* rel  = (const float*)d_in[3];
    const float* wout = (const float*)d_in[4];
    const float* bout = (const float*)d_in[5];
    float* out = (float*)d_out;
    char* ws = (char*)d_ws;

    const size_t XH = (size_t)MROWS * DMODEL;            // 8M elements
    f16* wqkvT = (f16*)(ws);                             // 6 MB
    f16* woutT = wqkvT + (size_t)3 * DMODEL * DMODEL;    // 2 MB
    f16* qbuf  = woutT + (size_t)DMODEL * DMODEL;        // 16 MB each
    f16* kbuf  = qbuf + XH;
    f16* vbuf  = kbuf + XH;
    f16* abuf  = vbuf + XH;

    prep<<<4096, 256, 0, stream>>>(wqkv, wqkvT, wout, woutT);

    // 1) QKV projection, A = x fp32 converted in-staging
    gemm_mfma<0, 1><<<dim3(3 * DMODEL / 128, MROWS / 128), 256, 0, stream>>>(
        x, nullptr, wqkvT, bqkv, 3 * DMODEL, DMODEL, nullptr, qbuf, kbuf, vbuf);

    // 2) attention
    attn_mfma<<<NB * NH, 512, 0, stream>>>(qbuf, kbuf, vbuf, rel, abuf);

    // 3) output projection, A = abuf f16
    gemm_mfma<1, 0><<<dim3(DMODEL / 128, MROWS / 128), 256, 0, stream>>>(
        nullptr, abuf, woutT, bout, DMODEL, DMODEL, out, nullptr, nullptr, nullptr);
}

// Round 7
// 237.482 us; speedup vs baseline: 1.2419x; 1.2419x over previous
//
#include <hip/hip_runtime.h>

#define SEQ    512
#define NH     16
#define DH     64
#define DMODEL 1024
#define NB     16
#define MROWS  (NB*SEQ)      // 8192
#define MAXL   512

typedef _Float16 f16;
typedef f16  f16x8 __attribute__((ext_vector_type(8)));
typedef f16  f16x4 __attribute__((ext_vector_type(4)));
typedef float f32x4 __attribute__((ext_vector_type(4)));

// async global->LDS, 16B/lane; global addr per-lane, LDS dest = wave-uniform base + lane*16
__device__ static inline void gll16(const f16* g, f16* l) {
    __builtin_amdgcn_global_load_lds(
        (const __attribute__((address_space(1))) void*)(g),
        (__attribute__((address_space(3))) void*)(l), 16, 0, 0);
}

// ---------------------------------------------------------------------------
// fused prep: x -> f16 (blocks 0..8191), wqkv -> f16 transposed (8192..11263),
// wout -> f16 transposed (11264..12287)
// ---------------------------------------------------------------------------
__global__ __launch_bounds__(256)
void prep(const float* __restrict__ x, f16* __restrict__ xh,
          const float* __restrict__ wqkv, f16* __restrict__ wqkvT,
          const float* __restrict__ wout, f16* __restrict__ woutT)
{
    const int bid = blockIdx.x, t = threadIdx.x;
    if (bid < 8192) {
        int i = (bid * 256 + t) * 4;
        float4 v = *(const float4*)(x + i);
        f16x4 h = { (f16)v.x, (f16)v.y, (f16)v.z, (f16)v.w };
        *(f16x4*)(xh + i) = h;
        return;
    }
    __shared__ float tile[32][33];
    const float* in; f16* out; int C, gx, gy;
    if (bid < 8192 + 3072) {
        int b2 = bid - 8192; in = wqkv; out = wqkvT; C = 3072;
        gx = b2 % 96; gy = b2 / 96;
    } else {
        int b2 = bid - 11264; in = wout; out = woutT; C = 1024;
        gx = b2 & 31; gy = b2 >> 5;
    }
    const int R = 1024;
    int tx = t & 31, ty = t >> 5;
    int c0 = gx * 32, r0 = gy * 32;
    #pragma unroll
    for (int i = 0; i < 4; ++i)
        tile[ty + i * 8][tx] = in[(size_t)(r0 + ty + i * 8) * C + c0 + tx];
    __syncthreads();
    #pragma unroll
    for (int i = 0; i < 4; ++i)
        out[(size_t)(c0 + ty + i * 8) * R + r0 + tx] = (f16)tile[tx][ty + i * 8];
}

// ---------------------------------------------------------------------------
// MFMA GEMM (R5-proven): C(M x N) = A(M x K) @ Bt(N x K)^T + bias
// 128x128 tile, BK=64, 256 threads, 16x16x32 f16, fp32 acc.
// Staging XOR-swizzle via per-lane global chunk permute -> conflict-free.
// MODE 0 epilogue (QKV): Q -> [b][h][n][d] plain
//                        K -> [b][h][n][d], d-chunk8 XOR (n&7)
//                        V -> [b][h][d][n] transposed, n-chunk8 XOR (d&7)
// MODE 1 epilogue: fp32 row-major C + bias
// ---------------------------------------------------------------------------
template<int MODE>
__global__ __launch_bounds__(256)
void gemm_mfma(const f16* __restrict__ A, const f16* __restrict__ Bt,
               const float* __restrict__ bias, int N, int K,
               float* __restrict__ Cout,
               f16* __restrict__ qb, f16* __restrict__ kb, f16* __restrict__ vb)
{
    __shared__ f16 As[128 * 64];
    __shared__ f16 Bs[128 * 64];
    const int t = threadIdx.x;
    const int lane = t & 63, w = t >> 6;
    const int quad = lane >> 4, l16 = lane & 15;
    const int xr = l16 & 7;
    const int m0 = blockIdx.y * 128, n0 = blockIdx.x * 128;
    const int wm = (w & 1) * 64, wn = (w >> 1) * 64;

    f32x4 acc[4][4];
    #pragma unroll
    for (int i = 0; i < 4; ++i)
        #pragma unroll
        for (int j = 0; j < 4; ++j)
            acc[i][j] = f32x4{0.f, 0.f, 0.f, 0.f};

    const int sr8 = lane >> 3;
    const int sc8 = (lane & 7) ^ sr8;
    const f16* agp = A  + (size_t)(m0 + w * 32 + sr8) * K + sc8 * 8;
    const f16* bgp = Bt + (size_t)(n0 + w * 32 + sr8) * K + sc8 * 8;
    f16* asl = As + w * 2048;
    f16* bsl = Bs + w * 2048;

    for (int k0 = 0; k0 < K; k0 += 64) {
        __syncthreads();
        #pragma unroll
        for (int c = 0; c < 4; ++c) {
            gll16(agp + k0 + c * 8 * K, asl + c * 512);
            gll16(bgp + k0 + c * 8 * K, bsl + c * 512);
        }
        __syncthreads();
        #pragma unroll
        for (int ks = 0; ks < 2; ++ks) {
            f16x8 af[4], bf[4];
            #pragma unroll
            for (int ms = 0; ms < 4; ++ms)
                af[ms] = *(const f16x8*)&As[(wm + ms * 16 + l16) * 64
                                            + (((ks * 4 + quad) ^ xr) * 8)];
            #pragma unroll
            for (int ns = 0; ns < 4; ++ns)
                bf[ns] = *(const f16x8*)&Bs[(wn + ns * 16 + l16) * 64
                                            + (((ks * 4 + quad) ^ xr) * 8)];
            #pragma unroll
            for (int ms = 0; ms < 4; ++ms)
                #pragma unroll
                for (int ns = 0; ns < 4; ++ns)
                    acc[ms][ns] = __builtin_amdgcn_mfma_f32_16x16x32_f16(
                        af[ms], bf[ns], acc[ms][ns], 0, 0, 0);
        }
    }

    // C/D layout: col = l16 (n), row = quad*4 + reg (m)
    if (MODE == 0) {
        #pragma unroll
        for (int ns = 0; ns < 4; ++ns) {
            int col = n0 + wn + ns * 16 + l16;
            float bv = bias[col];
            int which = col >> 10;
            int hh = (col & 1023) >> 6, d = col & 63;
            #pragma unroll
            for (int ms = 0; ms < 4; ++ms) {
                int rowb = m0 + wm + ms * 16 + quad * 4;
                int bb_ = rowb >> 9, n_ = rowb & 511;   // rowb%4==0
                if (which == 0) {
                    #pragma unroll
                    for (int reg = 0; reg < 4; ++reg)
                        qb[((size_t)(bb_ * NH + hh) * SEQ + n_ + reg) * DH + d] =
                            (f16)(acc[ms][ns][reg] + bv);
                } else if (which == 2) {
                    f16x4 pk;
                    #pragma unroll
                    for (int reg = 0; reg < 4; ++reg)
                        pk[reg] = (f16)(acc[ms][ns][reg] + bv);
                    int c8s = ((n_ >> 3) & 7) ^ (d & 7);
                    *(f16x4*)(vb + ((size_t)(bb_ * NH + hh) * DH + d) * SEQ
                                 + (n_ & ~63) + c8s * 8 + (n_ & 7)) = pk;
                } else {
                    #pragma unroll
                    for (int reg = 0; reg < 4; ++reg) {
                        int n = n_ + reg;
                        int dd = (((d >> 3) ^ (n & 7)) * 8) + (d & 7);
                        kb[((size_t)(bb_ * NH + hh) * SEQ + n) * DH + dd] =
                            (f16)(acc[ms][ns][reg] + bv);
                    }
                }
            }
        }
    } else {
        #pragma unroll
        for (int ns = 0; ns < 4; ++ns) {
            int col = n0 + wn + ns * 16 + l16;
            float bv = bias[col];
            #pragma unroll
            for (int ms = 0; ms < 4; ++ms) {
                int rowb = m0 + wm + ms * 16 + quad * 4;
                #pragma unroll
                for (int reg = 0; reg < 4; ++reg)
                    Cout[(size_t)(rowb + reg) * N + col] = acc[ms][ns][reg] + bv;
            }
        }
    }
}

// ---------------------------------------------------------------------------
// MFMA attention. Grid = 512 blocks (2 per (b,h); halfq = bid>>8 so paired
// blocks share an XCD for K/V L2 reuse). 256 threads = 4 waves; wave owns 64
// q-rows (4 chunks of 16); block owns 256 q-rows, stages all K/V for its
// head as 4 double-buffered 128-key tiles. LDS 76 KB -> 2 blocks/CU: one
// block computes while the other drains its prefetch at the barrier.
// Transposed-S (no online rescale: |s| << f16 overflow), per-lane scalar
// row-sum, quad-reduced once at the end.
// ---------------------------------------------------------------------------
__global__ __launch_bounds__(256, 2)
void attn_mfma(const f16* __restrict__ qb, const f16* __restrict__ kb,
               const f16* __restrict__ vb, const float* __restrict__ rel,
               f16* __restrict__ ob)
{
    __shared__ f16 Ks[2][128 * 64];   // [key][d-chunk8 ^ (key&7)]       32 KB
    __shared__ f16 Vt[2][64 * 128];   // [d][key; chunk8 ^ (d&7) per 64] 32 KB
    __shared__ f16 Pw[4][16 * 64];    // wave-private P                   8 KB
    __shared__ float relh[1024];      // rel[:,h] * log2(e)               4 KB

    const int t = threadIdx.x;
    const int lane = t & 63, w = t >> 6;
    const int quad = lane >> 4, l16 = lane & 15;
    const int xr = l16 & 7;
    const int bid = blockIdx.x;
    const int bh = bid & 255, halfq = bid >> 8;
    const int h = bh & 15, b = bh >> 4;
    const int q0 = halfq * 256;            // this block's q-row base

    for (int i = t; i < 2 * MAXL - 1; i += 256)
        relh[i] = rel[i * NH + h] * 1.44269504f;

    // Q B-fragments: chunk c -> Q[q0 + w*64 + c*16 + l16][quad*8 + j (+32)]
    f16x8 qf[4][2];
    #pragma unroll
    for (int c = 0; c < 4; ++c) {
        const f16* qrow = qb + ((size_t)bh * SEQ + q0 + w * 64 + c * 16 + l16) * DH
                        + quad * 8;
        qf[c][0] = *(const f16x8*)(qrow);
        qf[c][1] = *(const f16x8*)(qrow + 32);
    }

    f32x4 o[4][4];
    float lsum[4];
    #pragma unroll
    for (int c = 0; c < 4; ++c) {
        lsum[c] = 0.f;
        #pragma unroll
        for (int dt = 0; dt < 4; ++dt) o[c][dt] = f32x4{0.f, 0.f, 0.f, 0.f};
    }

    const f16* kbase = kb + (size_t)bh * SEQ * DH;
    const f16* vbase = vb + (size_t)bh * DH * SEQ;
    f16* pw = &Pw[w][0];

    // stage 128-key tile kt into buffer buf (4 waves; linear copies — global
    // layouts already carry the XOR swizzle)
    auto stage = [&](int kt, int buf) {
        #pragma unroll
        for (int r = 0; r < 4; ++r) {
            const f16* src = kbase
                + (size_t)(kt * 128 + r * 32 + w * 8 + (lane >> 3)) * DH
                + (lane & 7) * 8;
            gll16(src, Ks[buf] + r * 2048 + w * 512);
        }
        #pragma unroll
        for (int r = 0; r < 4; ++r) {
            const f16* src = vbase
                + (size_t)(r * 16 + w * 4 + (lane >> 4)) * SEQ
                + kt * 128 + ((lane >> 3) & 1) * 64 + (lane & 7) * 8;
            gll16(src, Vt[buf] + r * 2048 + w * 512);
        }
    };

    stage(0, 0);
    __syncthreads();

    for (int kt = 0; kt < 4; ++kt) {
        if (kt < 3) stage(kt + 1, (kt + 1) & 1);
        const f16* ks = Ks[kt & 1];
        const f16* vt = Vt[kt & 1];

        #pragma unroll
        for (int c = 0; c < 4; ++c) {
            // ---- S^T = K Q^T over 128 keys ----
            f32x4 sT[8];
            #pragma unroll
            for (int mt = 0; mt < 8; ++mt) {
                const f16* kr = &ks[(mt * 16 + l16) * 64];
                f16x8 a0 = *(const f16x8*)(kr + ((quad ^ xr) * 8));
                f16x8 a1 = *(const f16x8*)(kr + (((4 + quad) ^ xr) * 8));
                f32x4 s = f32x4{0.f, 0.f, 0.f, 0.f};
                s = __builtin_amdgcn_mfma_f32_16x16x32_f16(a0, qf[c][0], s, 0, 0, 0);
                s = __builtin_amdgcn_mfma_f32_16x16x32_f16(a1, qf[c][1], s, 0, 0, 0);
                sT[mt] = s;
            }

            const int cb0 = q0 + w * 64 + c * 16 + l16 + (MAXL - 1)
                          - kt * 128 - quad * 4;
            #pragma unroll
            for (int g = 0; g < 2; ++g) {
                #pragma unroll
                for (int m4 = 0; m4 < 4; ++m4) {
                    int mt = g * 4 + m4;
                    f16x4 pk;
                    #pragma unroll
                    for (int reg = 0; reg < 4; ++reg) {
                        float e = exp2f(fmaf(sT[mt][reg], 0.180336878f,
                                             relh[cb0 - mt * 16 - reg]));
                        lsum[c] += e;
                        pk[reg] = (f16)e;
                    }
                    int c8 = (m4 * 2 + (quad >> 1)) ^ xr;
                    *(f16x4*)&pw[l16 * 64 + c8 * 8 + (quad & 1) * 4] = pk;
                }
                __builtin_amdgcn_s_waitcnt(0xC07F);   // lgkmcnt(0), wave-private P

                #pragma unroll
                for (int s2 = 0; s2 < 2; ++s2) {
                    f16x8 pa = *(const f16x8*)&pw[l16 * 64 + (((s2 * 4 + quad) ^ xr) * 8)];
                    #pragma unroll
                    for (int dt = 0; dt < 4; ++dt) {
                        const f16* vr = &vt[(dt * 16 + l16) * 128 + g * 64];
                        f16x8 vb8 = *(const f16x8*)(vr + (((s2 * 4 + quad) ^ xr) * 8));
                        o[c][dt] = __builtin_amdgcn_mfma_f32_16x16x32_f16(
                            pa, vb8, o[c][dt], 0, 0, 0);
                    }
                }
            }
        }
        __syncthreads();   // drains prefetch vmcnt + joins waves
    }

    #pragma unroll
    for (int c = 0; c < 4; ++c) {
        float ls = lsum[c];
        ls += __shfl_xor(ls, 16, 64);
        ls += __shfl_xor(ls, 32, 64);
        #pragma unroll
        for (int reg = 0; reg < 4; ++reg) {
            float inv = 1.0f / __shfl(ls, quad * 4 + reg, 64);
            size_t rbase = ((size_t)b * SEQ + q0 + w * 64 + c * 16 + quad * 4 + reg)
                         * DMODEL + h * DH;
            #pragma unroll
            for (int dt = 0; dt < 4; ++dt)
                ob[rbase + dt * 16 + l16] = (f16)(o[c][dt][reg] * inv);
        }
    }
}

// ---------------------------------------------------------------------------
extern "C" void kernel_launch(void* const* d_in, const int* in_sizes, int n_in,
                              void* d_out, int out_size, void* d_ws, size_t ws_size,
                              hipStream_t stream)
{
    const float* x    = (const float*)d_in[0];
    const float* wqkv = (const float*)d_in[1];
    const float* bqkv = (const float*)d_in[2];
    const float* rel  = (const float*)d_in[3];
    const float* wout = (const float*)d_in[4];
    const float* bout = (const float*)d_in[5];
    float* out = (float*)d_out;
    char* ws = (char*)d_ws;

    const size_t XH = (size_t)MROWS * DMODEL;            // 8M elements
    f16* xh    = (f16*)(ws);
    f16* wqkvT = (f16*)(ws + 2 * XH);
    f16* woutT = wqkvT + (size_t)3 * DMODEL * DMODEL;
    f16* qbuf  = woutT + (size_t)DMODEL * DMODEL;
    f16* kbuf  = qbuf + XH;
    f16* vbuf  = kbuf + XH;
    f16* abuf  = vbuf + XH;

    prep<<<12288, 256, 0, stream>>>(x, xh, wqkv, wqkvT, wout, woutT);

    gemm_mfma<0><<<dim3(3 * DMODEL / 128, MROWS / 128), 256, 0, stream>>>(
        xh, wqkvT, bqkv, 3 * DMODEL, DMODEL, nullptr, qbuf, kbuf, vbuf);

    attn_mfma<<<2 * NB * NH, 256, 0, stream>>>(qbuf, kbuf, vbuf, rel, abuf);

    gemm_mfma<1><<<dim3(DMODEL / 128, MROWS / 128), 256, 0, stream>>>(
        abuf, woutT, bout, DMODEL, DMODEL, out, nullptr, nullptr, nullptr);
}